// Round 7
// baseline (263.924 us; speedup 1.0000x reference)
//
#include <hip/hip_runtime.h>
#include <math.h>

#define B_   32
#define L_   1024
#define BT_  (B_*L_)        // 32768
#define DIN  3
#define H_   512
#define NL   4
#define NS   64
#define DOUT 10
#define CT   128            // chunk length
#define NC   (L_/CT)        // 8 chunks
#define BH   (B_*H_)        // 16384

typedef __attribute__((ext_vector_type(8))) _Float16 f16x8;
typedef __attribute__((ext_vector_type(4))) float f32x4;

__device__ inline void gload16(const void* g, void* l) {
    __builtin_amdgcn_global_load_lds((const __attribute__((address_space(1))) void*)g,
                                     (__attribute__((address_space(3))) void*)l, 16, 0, 0);
}

__device__ inline unsigned packh2(float a, float b) {
    unsigned short lo = __builtin_bit_cast(unsigned short, (_Float16)a);
    unsigned short hi = __builtin_bit_cast(unsigned short, (_Float16)b);
    return (unsigned)lo | ((unsigned)hi << 16);
}
__device__ inline float lo16f(unsigned v) {
    return (float)__builtin_bit_cast(_Float16, (unsigned short)(v & 0xffffu));
}
__device__ inline float hi16f(unsigned v) {
    return (float)__builtin_bit_cast(_Float16, (unsigned short)(v >> 16));
}

// P' f16 swizzled address (row-major [128][64], col XORed to spread banks per 8-row stripe)
#define PSW(row, col) ((row) * 64 + ((col) ^ (((row) & 7) << 3)))

// raw barrier: drains LDS ops only, NOT vmcnt (global loads keep flying)
#define RAW_BARRIER() do { \
    asm volatile("s_waitcnt lgkmcnt(0)" ::: "memory"); \
    __builtin_amdgcn_s_barrier(); \
    asm volatile("" ::: "memory"); } while (0)

// ---------------- fused conv: P-MFMA -> in-LDS scan -> Y-MFMA (or ylast) ----------------
// Round-7: u-loop. 512 blocks (one per h), each block runs units u=0,1 (the old mh).
// Single dispatch round (512 = 2/CU x 256 CU); params/K/T32 computed once per pair;
// unit-1's X0 DMA issues UNDER unit-0's epilogue stores, X1 right after the
// store-reads drain -> one staging stall per CU hidden under compute.
// LDS map (reshuffled so [0,8K) is free during the epilogue):
//   X0 [0,8192h) | V [8192,16384h) | P' [16384,24576h) | X1/S0 [24576,32768h)
//   B' [0,24576h) after scan | epilogue tile Et [15360,32768h) (128x136)
// Region-safety: B' readers done at B7; Et writes post-B7; X0(u1) -> [0,8K) post-B8
// (disjoint from Et); X1(u1)+V(u1) -> inside old Et only after RAW_BARRIER (Et reads
// drained). Unit-1 B1 queue per wave = X0(2), stores(4), X1(2) -> vmcnt(2)=X0 ready,
// vmcnt(0) at B1.5 = X1 ready. Arithmetic untouched -> bit-identical output.
__global__ __launch_bounds__(512, 4) void conv_fused(const float* __restrict__ x,
                                                     const float* __restrict__ Wenc,
                                                     const float* __restrict__ log_dt,
                                                     const float* __restrict__ A_log,
                                                     const float* __restrict__ Cmat,
                                                     const float* __restrict__ WffL,
                                                     _Float16* __restrict__ WTl,
                                                     const _Float16* __restrict__ XT,
                                                     _Float16* __restrict__ YT,
                                                     float* __restrict__ ylast,
                                                     float* __restrict__ outz,
                                                     int layer, int doY) {
    __shared__ __align__(16) _Float16 smem[32768];      // 64KB
    __shared__ float Kl4[4][128];
    __shared__ float Kl[128];
    __shared__ unsigned T32[256];        // pair table: T32[d+128] = pack(K[d], K[d-1])
    __shared__ float dAs[64];
    __shared__ float wps[64];
    __shared__ float rTs[64];
    _Float16* X0l = smem;                // X half 0 [0,8192h)
    _Float16* Vl  = smem + 8192;         // V [64 n][128 j], dead after P-MFMA
    _Float16* Pl  = smem + 16384;        // P' [128][64] swizzled
    _Float16* X1l = smem + 24576;        // X half 1; overlaid by S0 after frag loads
    _Float16* S0l = smem + 24576;
    _Float16* Bp  = smem;                // B' [128 t][24 chunks] over [0,24576h)
    _Float16* Et  = smem + 15360;        // epilogue tile [15360,32768h): 128x136

    const int h = blockIdx.x;
    const int tid = threadIdx.x;
    const int w = tid >> 6, l = tid & 63;
    const int fr = l & 15, q = l >> 4;
    const int wm = w >> 1, wn = w & 1;   // unified decomp: P = 4x2(32x32), Y = 4x2(32x64)
    const int c = l & 7, rsub = l >> 3;

    float w0e = 0.f, w1e = 0.f, w2e = 0.f;
    if (layer == 0) { w0e = Wenc[h]; w1e = Wenc[H_ + h]; w2e = Wenc[2 * H_ + h]; }

    // stage one X half of unit u (layer0: compute from x, bit-identical fma)
    auto stageHalf = [&](int u, int s) {
        _Float16* dst = s ? X1l : X0l;
        if (layer == 0) {
#pragma unroll
            for (int ii = 0; ii < 2; ii++) {
                int t2 = w * 2 + ii;
                int rr = t2 * 8 + rsub;
                int srcc = c ^ (rr & 7);
                int bt = u * 16384 + rr * 128 + s * 64 + srcc * 8;
                const float* xp = x + (size_t)bt * DIN;
                f16x8 o;
#pragma unroll
                for (int e = 0; e < 8; e++)
                    o[e] = (_Float16)fmaf(xp[e * 3], w0e,
                                     fmaf(xp[e * 3 + 1], w1e, xp[e * 3 + 2] * w2e));
                *(f16x8*)&dst[t2 * 512 + l * 8] = o;
            }
        } else {
            const _Float16* Xu = XT + (size_t)h * BT_ + (size_t)u * 16384;
#pragma unroll
            for (int ii = 0; ii < 2; ii++) {
                int t2 = w * 2 + ii;
                int rr = t2 * 8 + rsub;
                int srcc = c ^ (rr & 7);
                gload16(Xu + (size_t)rr * 128 + s * 64 + srcc * 8,
                        &dst[t2 * 512 + l * 8]);
            }
        }
    };

    // ---- unit-0 prologue: stage X0 then X1 (X0 pair oldest in vm queue) ----
    stageHalf(0, 0);
    stageHalf(0, 1);
    if (layer == 0 && h == 0 && tid < B_ * DOUT) outz[tid] = 0.f;  // zero out for head atomics

    // ---- per-(layer,h) S4D params into LDS (once per block) ----
    if (tid < 64) {
        int n = tid;
        float dt  = expf(log_dt[layer * H_ + h]);
        float A   = -expf(A_log[((size_t)layer * H_ + h) * NS + n]);
        float dtA = dt * A;
        float r0  = expf(dtA);
        dAs[n] = dtA;
        wps[n] = Cmat[((size_t)layer * H_ + h) * NS + n] * ((r0 - 1.0f) / A);
        rTs[n] = expf(dtA * (float)CT);
    } else if (layer < 3 && tid < 128) {
        // distributed Wff->WT f16 transpose: 512 blocks x 64 thr = full 512x512
        int g = h * 64 + (tid - 64);
        int n = g >> 6, k8 = g & 63;
        const float* src = WffL + n;
        f16x8 o;
#pragma unroll
        for (int j = 0; j < 8; j++)
            o[j] = (_Float16)src[(size_t)(k8 * 8 + j) * H_];
        *(f16x8*)(WTl + (size_t)n * H_ + k8 * 8) = o;
    }
    RAW_BARRIER();                        // params LDS-visible; X gloads keep flying

    for (int u = 0; u < 2; u++) {
        // ---- V build (per unit; B' destroys it) + K partials (u0 only) ----
#pragma unroll
        for (int ii = 0; ii < 2; ii++) {  // V[n][j]=exp(dA_n*(127-j)), swizzled
            int slot = tid + 512 * ii;    // 1024 = 64n x 16c
            int n = slot >> 4, cc = slot & 15;
            float da = dAs[n];
            int jb = cc * 8;
            float cur  = __expf(da * (float)(127 - jb));
            float rinv = __expf(-da);
            f16x8 vv;
#pragma unroll
            for (int e = 0; e < 8; e++) { vv[e] = (_Float16)cur; cur *= rinv; }
            *(f16x8*)&Vl[n * 128 + ((cc >> 3) * 8 + ((cc & 7) ^ (n & 7))) * 8] = vv;
        }
        if (u == 0 && doY) {              // K[d] partials: group g sums n in [16g,16g+16)
            int t = tid & 127, g = tid >> 7;
            float k = 0.f, d = (float)t;
            for (int n = g * 16; n < g * 16 + 16; n++) k += wps[n] * __expf(dAs[n] * d);
            Kl4[g][t] = k;
        }
        // B1: X0 ready (2 youngest vm ops = X1 pair may fly); all LDS writes drained
        asm volatile("s_waitcnt vmcnt(2) lgkmcnt(0)" ::: "memory");
        __builtin_amdgcn_s_barrier();
        asm volatile("" ::: "memory");

        if (u == 0 && doY && tid < 128)
            Kl[tid] = (Kl4[0][tid] + Kl4[1][tid]) + (Kl4[2][tid] + Kl4[3][tid]);

        // ---- frag-load half 0, P-MFMA s=0 (covers X1 tail latency) ----
        f16x8 fA[2][2][2];                // [i][s][kk], all-static indexing
        f32x4 accP[2][2] = {};
#pragma unroll
        for (int i = 0; i < 2; i++)
#pragma unroll
            for (int kk = 0; kk < 2; kk++) {
                int row = wm * 32 + i * 16 + fr;
                int kc = kk * 4 + q;
                fA[i][0][kk] = *(const f16x8*)&X0l[row * 64 + ((kc ^ (row & 7)) * 8)];
            }
#pragma unroll
        for (int kk = 0; kk < 2; kk++) {
            int kc = kk * 4 + q;
            f16x8 bv[2];
#pragma unroll
            for (int j = 0; j < 2; j++) {
                int n = wn * 32 + j * 16 + fr;
                bv[j] = *(const f16x8*)&Vl[n * 128 + 0 * 64 + ((kc ^ (n & 7)) * 8)];
            }
#pragma unroll
            for (int i = 0; i < 2; i++)
#pragma unroll
                for (int j = 0; j < 2; j++)
                    accP[i][j] = __builtin_amdgcn_mfma_f32_16x16x32_f16(
                        fA[i][0][kk], bv[j], accP[i][j], 0, 0, 0);
        }

        // B1.5: X1 fully landed in LDS
        asm volatile("s_waitcnt vmcnt(0) lgkmcnt(0)" ::: "memory");
        __builtin_amdgcn_s_barrier();
        asm volatile("" ::: "memory");

        // ---- frag-load half 1, P-MFMA s=1 ----
#pragma unroll
        for (int i = 0; i < 2; i++)
#pragma unroll
            for (int kk = 0; kk < 2; kk++) {
                int row = wm * 32 + i * 16 + fr;
                int kc = kk * 4 + q;
                fA[i][1][kk] = *(const f16x8*)&X1l[row * 64 + ((kc ^ (row & 7)) * 8)];
            }
#pragma unroll
        for (int kk = 0; kk < 2; kk++) {
            int kc = kk * 4 + q;
            f16x8 bv[2];
#pragma unroll
            for (int j = 0; j < 2; j++) {
                int n = wn * 32 + j * 16 + fr;
                bv[j] = *(const f16x8*)&Vl[n * 128 + 1 * 64 + ((kc ^ (n & 7)) * 8)];
            }
#pragma unroll
            for (int i = 0; i < 2; i++)
#pragma unroll
                for (int j = 0; j < 2; j++)
                    accP[i][j] = __builtin_amdgcn_mfma_f32_16x16x32_f16(
                        fA[i][1][kk], bv[j], accP[i][j], 0, 0, 0);
        }

        // ---- P' f16 into Pl ----
#pragma unroll
        for (int i = 0; i < 2; i++)
#pragma unroll
            for (int j = 0; j < 2; j++)
#pragma unroll
                for (int tt = 0; tt < 4; tt++) {
                    int row = wm * 32 + i * 16 + q * 4 + tt;
                    int col = wn * 32 + j * 16 + fr;
                    Pl[PSW(row, col)] = (_Float16)accP[i][j][tt];
                }
        __syncthreads();                  // B4

        // ---- T32 pair table (u0 only): T32[d+128] = pack(K[d], K[d-1]), 0 for d<0 ----
        if (u == 0 && doY && tid < 256) {
            int d = tid - 128;
            unsigned short lo = 0, hi = 0;
            if (d >= 0) lo = __builtin_bit_cast(unsigned short, (_Float16)Kl[d]);
            if (d >= 1) hi = __builtin_bit_cast(unsigned short, (_Float16)Kl[d - 1]);
            T32[tid] = (unsigned)lo | ((unsigned)hi << 16);
        }

        // ---- scan (paired n): S0 -> LDS (doY) or ylast (last layer) ----
        {
            int bl = tid >> 5, n0 = (tid & 31) * 2;   // 512 slots = 16 bl x 32 n-pairs
            float rT0 = rTs[n0], rT1 = rTs[n0 + 1];
            float E0 = 0.f, E1 = 0.f;
            if (doY) {
#pragma unroll
                for (int cc = 0; cc < 8; cc++) {
                    int row = bl * 8 + cc;
                    *(unsigned*)&S0l[row * 64 + (((n0 >> 3) ^ (row & 7)) * 8) + (n0 & 7)] =
                        packh2(E0, E1);
                    unsigned pv = *(const unsigned*)&Pl[PSW(row, n0)];
                    E0 = fmaf(rT0, E0, lo16f(pv));
                    E1 = fmaf(rT1, E1, hi16f(pv));
                }
            } else {
#pragma unroll
                for (int cc = 0; cc < 8; cc++) {
                    int row = bl * 8 + cc;
                    unsigned pv = *(const unsigned*)&Pl[PSW(row, n0)];
                    E0 = fmaf(rT0, E0, lo16f(pv));
                    E1 = fmaf(rT1, E1, hi16f(pv));
                }
                float wE = fmaf(wps[n0], E0, wps[n0 + 1] * E1);
                wE += __shfl_xor(wE, 16);     // reduce over the 32 pair-lanes only
                wE += __shfl_xor(wE, 8);  wE += __shfl_xor(wE, 4);
                wE += __shfl_xor(wE, 2);  wE += __shfl_xor(wE, 1);
                if ((l & 31) == 0) ylast[(size_t)(u * 16 + bl) * H_ + h] = wE;
            }
        }
        if (!doY) {
            if (u == 0) {                 // stage unit-1 (both halves); V-build covers latency
                RAW_BARRIER();            // all Pl reads done; ylast store issued (oldest)
                stageHalf(1, 0);          // -> [0,8192h): u0's X0 dead since B1.5
                stageHalf(1, 1);          // -> [24576h): u0's X1 dead since B4
            }
            continue;
        }
        __syncthreads();                  // B5: P' reads done; smem[0:24576h) free

        // ---- build B' [128 t][24 chunks] over X0/V/P' regions ----
        {                                 // Wr part (paired n): B'[t][128+n] = w_n r_n^(t+1)
            int n0 = (tid & 31) * 2, tc = tid >> 5;   // 512 slots = 16 tc x 32 n-pairs
            int t0 = tc * 8;
            float ra0 = __expf(dAs[n0]),     ra1 = __expf(dAs[n0 + 1]);
            float c0  = wps[n0] * __expf(dAs[n0] * (float)(t0 + 1));
            float c1  = wps[n0 + 1] * __expf(dAs[n0 + 1] * (float)(t0 + 1));
#pragma unroll
            for (int e = 0; e < 8; e++) { // (t0+e)&7 == e
                *(unsigned*)&Bp[(t0 + e) * 192 + (16 + ((n0 >> 3) ^ e)) * 8 + (n0 & 7)] =
                    packh2(c0, c1);
                c0 *= ra0; c1 *= ra1;
            }
        }
#pragma unroll
        for (int ii = 0; ii < 4; ii++) {  // T part via pair table: 4 u32 per chunk
            int slot = tid + 512 * ii;    // 2048 = 128t x 16c
            int t = slot >> 4, cc = slot & 15;
            unsigned* bp32 = (unsigned*)&Bp[t * 192 + ((cc >> 3) * 8 + ((cc & 7) ^ (t & 7))) * 8];
            int base = t - cc * 8 + 128;  // d = t - jb - 2p; idx = d+128 in [2,255]
#pragma unroll
            for (int p = 0; p < 4; p++)
                bp32[p] = T32[base - 2 * p];
        }
        __syncthreads();                  // B6: B' ready

        // ---- Y-MFMA [128 bc][128 t], K=192 (Xreg,Xreg,S0); waves 4x2 (32x64 tiles) ----
        f32x4 acc[2][4] = {};
#pragma unroll
        for (int s = 0; s < 3; s++)
#pragma unroll
            for (int kk = 0; kk < 2; kk++) {
                int kc = kk * 4 + q;
                f16x8 av[2], bv[4];
#pragma unroll
                for (int i = 0; i < 2; i++) {
                    int row = wm * 32 + i * 16 + fr;
                    av[i] = (s < 2) ? fA[i][s][kk]
                                    : *(const f16x8*)&S0l[row * 64 + ((kc ^ (row & 7)) * 8)];
                }
#pragma unroll
                for (int j = 0; j < 4; j++) {
                    int tc = wn * 64 + j * 16 + fr;
                    bv[j] = *(const f16x8*)&Bp[tc * 192 + (s * 8 + (kc ^ (tc & 7))) * 8];
                }
#pragma unroll
                for (int i = 0; i < 2; i++)
#pragma unroll
                    for (int j = 0; j < 4; j++)
                        acc[i][j] = __builtin_amdgcn_mfma_f32_16x16x32_f16(
                            av[i], bv[j], acc[i][j], 0, 0, 0);
            }

        // ---- epilogue: Y tile -> Et [128][136] -> f16x8 coalesced stores ----
        __syncthreads();                  // B7: all MFMA LDS reads (B', S0) done
#pragma unroll
        for (int i = 0; i < 2; i++)
#pragma unroll
            for (int j = 0; j < 4; j++)
#pragma unroll
                for (int tt = 0; tt < 4; tt++) {
                    int row = wm * 32 + i * 16 + q * 4 + tt;
                    int col = wn * 64 + j * 16 + fr;
                    Et[row * 136 + col] = (_Float16)acc[i][j][tt];
                }
        __syncthreads();                  // B8
        if (u == 0) stageHalf(1, 0);      // prefetch u1's X0 -> [0,8192h) under the stores
        _Float16* Yp = YT + (size_t)h * BT_ + (size_t)u * 16384;
#pragma unroll
        for (int k2 = 0; k2 < 4; k2++) {
            int ch = tid + 512 * k2;      // 2048 = 128 rows x 16 chunks
            int r = ch >> 4, c8 = ch & 15;
            *(f16x8*)(Yp + (size_t)r * 128 + c8 * 8) = *(const f16x8*)&Et[r * 136 + c8 * 8];
        }
        RAW_BARRIER();                    // all waves' Et LDS reads done; stores fly
        if (u == 0) stageHalf(1, 1);      // u1's X1 -> [24576h) (inside old Et, now free)
    }
}

// ---------------- FFN GEMM in h-major: OutT[n][bt] = relu(sum_k WT[n][k]*YT[k][bt]) ----------------
// 512-thread blocks, 128n x 256bt tiles, grid 512 linear = 2 blocks/CU, no tail.
// XCD-chunked swizzle + counted-vmcnt raw-barrier K-loop (unchanged from r6).
__global__ __launch_bounds__(512, 4) void ffn_gemm_T(
    const _Float16* __restrict__ WT,   // [512 n][512 k]
    const _Float16* __restrict__ YT,   // [512 k][BT_]
    _Float16* __restrict__ OT)         // [512 n][BT_], relu applied
{
    __shared__ __align__(16) _Float16 pool[29184];   // As[3][4096] + Bs[2][8448] = 58368 B
    _Float16* As0 = pool;
    _Float16* Bs0 = pool + 12288;
    const int tid = threadIdx.x;
    const int l = tid & 63, w = tid >> 6;            // 8 waves
    const int bid = blockIdx.x;                      // 512 linear
    const int xcd = bid & 7, slot = bid >> 3;        // bijective XCD-chunk map
    const int bt0 = (xcd * 16 + (slot >> 2)) * 256;
    const int bn  = (slot & 3) * 128;
    const int srow = l >> 2, schunk = (l & 3) ^ ((l >> 3) & 3);
    const _Float16* ga0 = WT + (size_t)(bn + w * 16 + srow) * H_ + schunk * 8;
    const int btg = tid & 15, kp = (tid >> 4) & 15, bth = tid >> 8;
    const _Float16* gb = YT + (size_t)(kp * 2) * BT_ + bt0 + bth * 128 + btg * 8;

    f16x8 stB[2][2];                     // [stage = k&1][b0/b1]; static idx under unroll
    f32x4 acc[4][4] = {};

    auto loadB = [&](int ks, int st) {
        stB[st][0] = *(const f16x8*)(gb + (size_t)(ks * 32) * BT_);
        stB[st][1] = *(const f16x8*)(gb + (size_t)(ks * 32 + 1) * BT_);
    };
    auto stageA = [&](int ks, int buf) {
        gload16(ga0 + ks * 32, As0 + buf * 4096 + w * 512);
    };
    auto writeB = [&](int st, int buf) {
        const int kpc = kp >> 2, kps = kp & 3;
#pragma unroll
        for (int e = 0; e < 8; e++) {
            int row = bth * 128 + btg * 8 + e;
            int off = row * 32 + (row >> 3) * 8 + ((kpc ^ ((row >> 1) & 3)) * 8) + kps * 2;
            _Float16 lo = stB[st][0][e], hi = stB[st][1][e];
            unsigned v = (unsigned)__builtin_bit_cast(unsigned short, lo)
                       | ((unsigned)__builtin_bit_cast(unsigned short, hi) << 16);
            *(unsigned*)&Bs0[buf * 8448 + off] = v;
        }
    };

    // prologue: B k=0,1 to regs; A k=0,1 staged; write B k=0
    loadB(0, 0);
    loadB(1, 1);
    __builtin_amdgcn_sched_barrier(0);
    stageA(0, 0);
    stageA(1, 1);
    writeB(0, 0);                         // implicit wait retires loadB(0)
    asm volatile("s_waitcnt vmcnt(1) lgkmcnt(0)" ::: "memory");   // As[0] ready; A(1) flies
    __builtin_amdgcn_s_barrier();
    asm volatile("" ::: "memory");

    const int wm = w >> 2, wn = w & 3;    // 2x4 waves, 64x64 tiles over 128x256
    const int fr = l & 15, q = l >> 4;
    const int axor = ((fr >> 1) & 3);
#pragma unroll
    for (int ks = 0; ks < 16; ks++) {
        const int a_cur = ks % 3;
        const int b_cur = ks & 1;
        if (ks + 2 < 16) {
            loadB(ks + 2, b_cur);                     // B before A: writeB's implicit wait
            __builtin_amdgcn_sched_barrier(0);        // won't drain the young stageA
            stageA(ks + 2, (ks + 2) % 3);
        }
        f16x8 av[4], bv[4];
#pragma unroll
        for (int i = 0; i < 4; i++) {
            int row = wm * 64 + i * 16 + fr;
            av[i] = *(const f16x8*)&As0[a_cur * 4096 + row * 32 + ((q ^ axor) * 8)];
        }
#pragma unroll
        for (int j = 0; j < 4; j++) {
            int row = wn * 64 + j * 16 + fr;
            bv[j] = *(const f16x8*)&Bs0[b_cur * 8448 + row * 32 + (row >> 3) * 8
                                        + ((q ^ ((row >> 1) & 3)) * 8)];
        }
#pragma unroll
        for (int i = 0; i < 4; i++)
#pragma unroll
            for (int j = 0; j < 4; j++)
                acc[i][j] = __builtin_amdgcn_mfma_f32_16x16x32_f16(av[i], bv[j], acc[i][j], 0, 0, 0);
        if (ks + 1 < 16) {
            writeB((ks + 1) & 1, b_cur ^ 1);          // Bs[b_cur^1] reads drained last barrier
            if (ks + 2 < 16)
                asm volatile("s_waitcnt vmcnt(3) lgkmcnt(0)" ::: "memory");  // A(ks+1) done; A(ks+2)+B(ks+2) fly
            else
                asm volatile("s_waitcnt vmcnt(0) lgkmcnt(0)" ::: "memory");  // tail: drain all
            __builtin_amdgcn_s_barrier();
            asm volatile("" ::: "memory");
        }
    }
    // close the pipeline before reusing pool for the epilogue
    asm volatile("s_waitcnt lgkmcnt(0)" ::: "memory");
    __builtin_amdgcn_s_barrier();
    asm volatile("" ::: "memory");

    // ---- epilogue: relu(C) -> LDS [64][264] per row-half -> f16x8 coalesced stores ----
#pragma unroll
    for (int half = 0; half < 2; half++) {
        if (half) __syncthreads();
        if (wm == half) {
#pragma unroll
            for (int i = 0; i < 4; i++)
#pragma unroll
                for (int j = 0; j < 4; j++)
#pragma unroll
                    for (int tt = 0; tt < 4; tt++) {
                        int r  = i * 16 + q * 4 + tt;          // 0..63 within half
                        int cc = wn * 64 + j * 16 + fr;        // 0..255
                        pool[r * 264 + cc] = (_Float16)fmaxf(acc[i][j][tt], 0.f);
                    }
        }
        __syncthreads();
#pragma unroll
        for (int k2 = 0; k2 < 4; k2++) {
            int ch = tid + 512 * k2;      // 2048 = 64 rows x 32 chunks
            int r = ch >> 5, c8 = ch & 31;
            *(f16x8*)(OT + (size_t)(bn + half * 64 + r) * BT_ + bt0 + c8 * 8) =
                *(const f16x8*)&pool[r * 264 + c8 * 8];
        }
    }
}

// ---------------- final head v2: 256 blocks = (b, 64-wide t-slice) ----------------
__global__ __launch_bounds__(512) void final_head2(const float* __restrict__ ylast,
                                                   const float* __restrict__ Wff3,
                                                   const float* __restrict__ Wdec,
                                                   float* __restrict__ out) {
    int bid = blockIdx.x;                 // 256 = 32 b x 8 s
    int b = bid >> 3, s = bid & 7;
    int tid = threadIdx.x;                // 512
    __shared__ float yrow[H_];
    __shared__ float hpart[8][64];
    yrow[tid] = ylast[(size_t)b * H_ + tid];
    __syncthreads();
    int kg = tid >> 6, tl = tid & 63;
    int t = s * 64 + tl;
    float acc = 0.f;
    const float* wcol = Wff3 + t;
    for (int k = kg * 64; k < kg * 64 + 64; k++)
        acc = fmaf(yrow[k], wcol[(size_t)k * H_], acc);
    hpart[kg][tl] = acc;
    __syncthreads();
    if (tid < 64) {
        float hv = 0.f;
#pragma unroll
        for (int g = 0; g < 8; g++) hv += hpart[g][tid];
        hv = fmaxf(hv, 0.f);              // h[t], t = s*64+tid, held by lane tid
#pragma unroll
        for (int d = 0; d < DOUT; d++) {
            float v = hv * Wdec[(size_t)(s * 64 + tid) * DOUT + d];
            v += __shfl_xor(v, 32); v += __shfl_xor(v, 16);
            v += __shfl_xor(v, 8);  v += __shfl_xor(v, 4);
            v += __shfl_xor(v, 2);  v += __shfl_xor(v, 1);
            if (tid == 0) atomicAdd(&out[(size_t)b * DOUT + d], v);
        }
    }
}

extern "C" void kernel_launch(void* const* d_in, const int* in_sizes, int n_in,
                              void* d_out, int out_size, void* d_ws, size_t ws_size,
                              hipStream_t stream) {
    const float* x      = (const float*)d_in[0];
    const float* Wenc   = (const float*)d_in[1];
    const float* log_dt = (const float*)d_in[2];
    const float* A_log  = (const float*)d_in[3];
    const float* Cmat   = (const float*)d_in[4];
    const float* Wff    = (const float*)d_in[5];
    const float* Wdec   = (const float*)d_in[6];
    float* out = (float*)d_out;

    char* ws = (char*)d_ws;
    _Float16* bufA  = (_Float16*)(ws);                   // 33554432 B  XT [512][32768]
    _Float16* bufB  = (_Float16*)(ws + 33554432);        // 33554432 B  YT
    _Float16* WT    = (_Float16*)(ws + 68681728);        // 1572864 B
    float*    ylast = (float*)(ws + 70254592);           // 65536 B

    for (int l = 0; l < NL; l++) {
        if (l < NL - 1) {
            conv_fused<<<H_, 512, 0, stream>>>(x, Wenc, log_dt, A_log, Cmat,
                                               Wff + (size_t)l * H_ * H_,
                                               WT + (size_t)l * H_ * H_,
                                               bufA, bufB, ylast, out, l, 1);
            ffn_gemm_T<<<512, 512, 0, stream>>>(
                WT + (size_t)l * H_ * H_, bufB, bufA);
        } else {
            conv_fused<<<H_, 512, 0, stream>>>(x, Wenc, log_dt, A_log, Cmat,
                                               Wff + (size_t)l * H_ * H_,
                                               WT,           // unused (doY=0, layer==3)
                                               bufA, bufB, ylast, out, l, 0);
            final_head2<<<B_ * 8, 512, 0, stream>>>(ylast, Wff + (size_t)l * H_ * H_, Wdec, out);
        }
    }
}

// Round 8
// 175.324 us; speedup vs baseline: 1.5054x; 1.5054x over previous
//
#include <hip/hip_runtime.h>
#include <math.h>

#define B_   32
#define L_   1024
#define BT_  (B_*L_)        // 32768
#define DIN  3
#define H_   512
#define NL   4
#define NS   64
#define DOUT 10
#define CT   128            // chunk length
#define NC   (L_/CT)        // 8 chunks
#define BH   (B_*H_)        // 16384

typedef __attribute__((ext_vector_type(8))) _Float16 f16x8;
typedef __attribute__((ext_vector_type(4))) float f32x4;

__device__ inline void gload16(const void* g, void* l) {
    __builtin_amdgcn_global_load_lds((const __attribute__((address_space(1))) void*)g,
                                     (__attribute__((address_space(3))) void*)l, 16, 0, 0);
}

__device__ inline unsigned packh2(float a, float b) {
    unsigned short lo = __builtin_bit_cast(unsigned short, (_Float16)a);
    unsigned short hi = __builtin_bit_cast(unsigned short, (_Float16)b);
    return (unsigned)lo | ((unsigned)hi << 16);
}
__device__ inline float lo16f(unsigned v) {
    return (float)__builtin_bit_cast(_Float16, (unsigned short)(v & 0xffffu));
}
__device__ inline float hi16f(unsigned v) {
    return (float)__builtin_bit_cast(_Float16, (unsigned short)(v >> 16));
}

// P' f16 swizzled address (row-major [128][64], col XORed to spread banks per 8-row stripe)
#define PSW(row, col) ((row) * 64 + ((col) ^ (((row) & 7) << 3)))

// raw barrier: drains LDS ops only, NOT vmcnt (global loads keep flying)
#define RAW_BARRIER() do { \
    asm volatile("s_waitcnt lgkmcnt(0)" ::: "memory"); \
    __builtin_amdgcn_s_barrier(); \
    asm volatile("" ::: "memory"); } while (0)

// ---------------- fused conv: P-MFMA -> in-LDS scan -> Y-MFMA (or ylast) ----------------
// block = (h, mh): rows 0..127 = 16 local batches x 8 chunks; 8 waves, 2 blocks/CU.
// Grid = 1024 blocks (2x residency): the dispatch queue backfills finished blocks,
// keeping co-resident blocks PHASE-STAGGERED (one stages from HBM while the other
// computes). Round-7 proved removing this (512 phase-locked blocks) costs 2x.
// Staging: X0's two gload16 issued FIRST (oldest in the per-wave vm queue), so B1
// waits only vmcnt(2) (X0 ready, X1 flying). frag-load-half0 + P-MFMA s=0 cover
// X1's tail; B1.5 (vmcnt 0) gates the half-1 fragment loads.
__global__ __launch_bounds__(512, 4) void conv_fused(const float* __restrict__ x,
                                                     const float* __restrict__ Wenc,
                                                     const float* __restrict__ log_dt,
                                                     const float* __restrict__ A_log,
                                                     const float* __restrict__ Cmat,
                                                     const float* __restrict__ WffL,
                                                     _Float16* __restrict__ WTl,
                                                     const _Float16* __restrict__ XT,
                                                     _Float16* __restrict__ YT,
                                                     float* __restrict__ ylast,
                                                     float* __restrict__ outz,
                                                     int layer, int doY) {
    __shared__ __align__(16) _Float16 smem[32768];      // 64KB
    __shared__ float Kl4[4][128];
    __shared__ float Kl[128];
    __shared__ unsigned T32[256];        // pair table: T32[d+128] = pack(K[d], K[d-1])
    __shared__ float dAs[64];
    __shared__ float wps[64];
    __shared__ float rTs[64];
    _Float16* Vl  = smem;                // [64 n][128 j] f16, dead after P-MFMA
    _Float16* Xh0 = smem + 8192;         // X half 0 (swizzled)
    _Float16* Pl  = smem + 16384;        // P' [128][64] swizzled
    _Float16* X1r = smem + 24576;        // X half 1; overlaid by S0 after frag loads
    _Float16* S0l = smem + 24576;
    _Float16* Bp  = smem;                // B' [128 t][24 chunks], after V/X0/P' dead

    int bid = blockIdx.x;
    int h = bid >> 1, mh = bid & 1;
    int tid = threadIdx.x;
    int w = tid >> 6, l = tid & 63;
    const int fr = l & 15, q = l >> 4;
    const int wm = w >> 1, wn = w & 1;   // unified decomp: P = 4x2(32x32), Y = 4x2(32x64)
    const _Float16* Xh = XT + (size_t)h * BT_ + (size_t)mh * 16384;

    const int c = l & 7, rsub = l >> 3;
    float w0e = 0.f, w1e = 0.f, w2e = 0.f;
    if (layer == 0) { w0e = Wenc[h]; w1e = Wenc[H_ + h]; w2e = Wenc[2 * H_ + h]; }

    // ---- stage BOTH X halves up-front (X0 pair issued first: oldest in vm queue) ----
    if (layer == 0) {                     // compute from x (cache-resident), bit-identical fma
        if (bid == 0 && tid < B_ * DOUT) outz[tid] = 0.f;   // zero `out` for head atomics
#pragma unroll
        for (int s = 0; s < 2; s++) {
            _Float16* dst = s ? X1r : Xh0;
#pragma unroll
            for (int ii = 0; ii < 2; ii++) {
                int t2 = w * 2 + ii;
                int rr = t2 * 8 + rsub;
                int srcc = c ^ (rr & 7);
                int bt = mh * 16384 + rr * 128 + s * 64 + srcc * 8;
                const float* xp = x + (size_t)bt * DIN;
                f16x8 o;
#pragma unroll
                for (int e = 0; e < 8; e++)
                    o[e] = (_Float16)fmaf(xp[e * 3], w0e,
                                     fmaf(xp[e * 3 + 1], w1e, xp[e * 3 + 2] * w2e));
                *(f16x8*)&dst[t2 * 512 + l * 8] = o;
            }
        }
    } else {
#pragma unroll
        for (int s = 0; s < 2; s++) {
            _Float16* dst = s ? X1r : Xh0;
#pragma unroll
            for (int ii = 0; ii < 2; ii++) {
                int t2 = w * 2 + ii;
                int rr = t2 * 8 + rsub;
                int srcc = c ^ (rr & 7);
                gload16(Xh + (size_t)rr * 128 + s * 64 + srcc * 8,
                        &dst[t2 * 512 + l * 8]);
            }
        }
    }

    // ---- per-(layer,h) S4D params into LDS ----
    if (tid < 64) {
        int n = tid;
        float dt  = expf(log_dt[layer * H_ + h]);
        float A   = -expf(A_log[((size_t)layer * H_ + h) * NS + n]);
        float dtA = dt * A;
        float r0  = expf(dtA);
        dAs[n] = dtA;
        wps[n] = Cmat[((size_t)layer * H_ + h) * NS + n] * ((r0 - 1.0f) / A);
        rTs[n] = expf(dtA * (float)CT);
    } else if (layer < 3 && tid < 96) {
        // ---- distributed Wff->WT f16 transpose ----
        int g = bid * 32 + (tid - 64);    // 1024 blocks x 32 = full 512x512
        int n = g >> 6, k8 = g & 63;
        const float* src = WffL + n;
        f16x8 o;
#pragma unroll
        for (int j = 0; j < 8; j++)
            o[j] = (_Float16)src[(size_t)(k8 * 8 + j) * H_];
        *(f16x8*)(WTl + (size_t)n * H_ + k8 * 8) = o;
    }
    RAW_BARRIER();   // params LDS-visible to ALL waves; lgkm-only: X gload16s keep flying

    // ---- V build (geometric exp) + parallel K partials ----
#pragma unroll
    for (int ii = 0; ii < 2; ii++) {      // V[n][j]=exp(dA_n*(127-j)), swizzled
        int slot = tid + 512 * ii;        // 1024 = 64n x 16c
        int n = slot >> 4, cc = slot & 15;
        float da = dAs[n];
        int jb = cc * 8;
        float cur  = __expf(da * (float)(127 - jb));
        float rinv = __expf(-da);
        f16x8 vv;
#pragma unroll
        for (int e = 0; e < 8; e++) { vv[e] = (_Float16)cur; cur *= rinv; }
        *(f16x8*)&Vl[n * 128 + ((cc >> 3) * 8 + ((cc & 7) ^ (n & 7))) * 8] = vv;
    }
    if (doY) {                            // K[d] partials: group g sums n in [16g,16g+16)
        int t = tid & 127, g = tid >> 7;
        float k = 0.f, d = (float)t;
        for (int n = g * 16; n < g * 16 + 16; n++) k += wps[n] * __expf(dAs[n] * d);
        Kl4[g][t] = k;
    }
    // B1: X0 (2 oldest vm ops per wave) + all LDS writes ready; X1 keeps flying
    asm volatile("s_waitcnt vmcnt(2) lgkmcnt(0)" ::: "memory");
    __builtin_amdgcn_s_barrier();
    asm volatile("" ::: "memory");

    if (doY && tid < 128)
        Kl[tid] = (Kl4[0][tid] + Kl4[1][tid]) + (Kl4[2][tid] + Kl4[3][tid]);

    // ---- frag-load half 0, P-MFMA s=0 (covers X1 tail latency) ----
    f16x8 fA[2][2][2];                    // [i][s][kk], all-static indexing
    f32x4 accP[2][2] = {};
#pragma unroll
    for (int i = 0; i < 2; i++)
#pragma unroll
        for (int kk = 0; kk < 2; kk++) {
            int row = wm * 32 + i * 16 + fr;
            int kc = kk * 4 + q;
            fA[i][0][kk] = *(const f16x8*)&Xh0[row * 64 + ((kc ^ (row & 7)) * 8)];
        }
#pragma unroll
    for (int kk = 0; kk < 2; kk++) {
        int kc = kk * 4 + q;
        f16x8 bv[2];
#pragma unroll
        for (int j = 0; j < 2; j++) {
            int n = wn * 32 + j * 16 + fr;
            bv[j] = *(const f16x8*)&Vl[n * 128 + 0 * 64 + ((kc ^ (n & 7)) * 8)];
        }
#pragma unroll
        for (int i = 0; i < 2; i++)
#pragma unroll
            for (int j = 0; j < 2; j++)
                accP[i][j] = __builtin_amdgcn_mfma_f32_16x16x32_f16(
                    fA[i][0][kk], bv[j], accP[i][j], 0, 0, 0);
    }

    // B1.5: X1 fully landed in LDS
    asm volatile("s_waitcnt vmcnt(0) lgkmcnt(0)" ::: "memory");
    __builtin_amdgcn_s_barrier();
    asm volatile("" ::: "memory");

    // ---- frag-load half 1, P-MFMA s=1 ----
#pragma unroll
    for (int i = 0; i < 2; i++)
#pragma unroll
        for (int kk = 0; kk < 2; kk++) {
            int row = wm * 32 + i * 16 + fr;
            int kc = kk * 4 + q;
            fA[i][1][kk] = *(const f16x8*)&X1r[row * 64 + ((kc ^ (row & 7)) * 8)];
        }
#pragma unroll
    for (int kk = 0; kk < 2; kk++) {
        int kc = kk * 4 + q;
        f16x8 bv[2];
#pragma unroll
        for (int j = 0; j < 2; j++) {
            int n = wn * 32 + j * 16 + fr;
            bv[j] = *(const f16x8*)&Vl[n * 128 + 1 * 64 + ((kc ^ (n & 7)) * 8)];
        }
#pragma unroll
        for (int i = 0; i < 2; i++)
#pragma unroll
            for (int j = 0; j < 2; j++)
                accP[i][j] = __builtin_amdgcn_mfma_f32_16x16x32_f16(
                    fA[i][1][kk], bv[j], accP[i][j], 0, 0, 0);
    }

    // ---- P' f16 into Pl ----
#pragma unroll
    for (int i = 0; i < 2; i++)
#pragma unroll
        for (int j = 0; j < 2; j++)
#pragma unroll
            for (int tt = 0; tt < 4; tt++) {
                int row = wm * 32 + i * 16 + q * 4 + tt;
                int col = wn * 32 + j * 16 + fr;
                Pl[PSW(row, col)] = (_Float16)accP[i][j][tt];
            }
    __syncthreads();                      // B4

    // ---- T32 pair table (doY): T32[d+128] = pack(K[d], K[d-1]), zeros for d<0 ----
    if (doY && tid < 256) {
        int d = tid - 128;
        unsigned short lo = 0, hi = 0;
        if (d >= 0) lo = __builtin_bit_cast(unsigned short, (_Float16)Kl[d]);
        if (d >= 1) hi = __builtin_bit_cast(unsigned short, (_Float16)Kl[d - 1]);
        T32[tid] = (unsigned)lo | ((unsigned)hi << 16);
    }

    // ---- scan (paired n): S0 -> LDS (doY, overlays X1) or ylast (last layer) ----
    {
        int bl = tid >> 5, n0 = (tid & 31) * 2;   // 512 slots = 16 bl x 32 n-pairs
        float rT0 = rTs[n0], rT1 = rTs[n0 + 1];
        float E0 = 0.f, E1 = 0.f;
        if (doY) {
#pragma unroll
            for (int cc = 0; cc < 8; cc++) {
                int row = bl * 8 + cc;
                *(unsigned*)&S0l[row * 64 + (((n0 >> 3) ^ (row & 7)) * 8) + (n0 & 7)] =
                    packh2(E0, E1);
                unsigned pv = *(const unsigned*)&Pl[PSW(row, n0)];
                E0 = fmaf(rT0, E0, lo16f(pv));
                E1 = fmaf(rT1, E1, hi16f(pv));
            }
        } else {
#pragma unroll
            for (int cc = 0; cc < 8; cc++) {
                int row = bl * 8 + cc;
                unsigned pv = *(const unsigned*)&Pl[PSW(row, n0)];
                E0 = fmaf(rT0, E0, lo16f(pv));
                E1 = fmaf(rT1, E1, hi16f(pv));
            }
            float wE = fmaf(wps[n0], E0, wps[n0 + 1] * E1);
            wE += __shfl_xor(wE, 16);     // reduce over the 32 pair-lanes only
            wE += __shfl_xor(wE, 8);  wE += __shfl_xor(wE, 4);
            wE += __shfl_xor(wE, 2);  wE += __shfl_xor(wE, 1);
            if ((l & 31) == 0) ylast[(size_t)(mh * 16 + bl) * H_ + h] = wE;
        }
    }
    if (!doY) return;
    __syncthreads();                      // B5: P' reads done; smem[0:24576h) free

    // ---- build B' [128 t][24 chunks] over V/X0/P' regions ----
    {                                     // Wr part (paired n): B'[t][128+n] = w_n r_n^(t+1)
        int n0 = (tid & 31) * 2, tc = tid >> 5;   // 512 slots = 16 tc x 32 n-pairs
        int t0 = tc * 8;
        float ra0 = __expf(dAs[n0]),     ra1 = __expf(dAs[n0 + 1]);
        float c0  = wps[n0] * __expf(dAs[n0] * (float)(t0 + 1));
        float c1  = wps[n0 + 1] * __expf(dAs[n0 + 1] * (float)(t0 + 1));
#pragma unroll
        for (int e = 0; e < 8; e++) {     // (t0+e)&7 == e
            *(unsigned*)&Bp[(t0 + e) * 192 + (16 + ((n0 >> 3) ^ e)) * 8 + (n0 & 7)] =
                packh2(c0, c1);
            c0 *= ra0; c1 *= ra1;
        }
    }
#pragma unroll
    for (int ii = 0; ii < 4; ii++) {      // T part via pair table: 4 u32 per chunk
        int slot = tid + 512 * ii;        // 2048 = 128t x 16c
        int t = slot >> 4, cc = slot & 15;
        unsigned* bp32 = (unsigned*)&Bp[t * 192 + ((cc >> 3) * 8 + ((cc & 7) ^ (t & 7))) * 8];
        int base = t - cc * 8 + 128;      // d = t - jb - 2p; idx = d+128 in [2,255]
#pragma unroll
        for (int p = 0; p < 4; p++)
            bp32[p] = T32[base - 2 * p];
    }
    __syncthreads();                      // B6: B' ready

    // ---- Y-MFMA [128 bc][128 t], K=192 (Xreg,Xreg,S0); waves 4x2 (32x64 tiles) ----
    f32x4 acc[2][4] = {};
#pragma unroll
    for (int s = 0; s < 3; s++)
#pragma unroll
        for (int kk = 0; kk < 2; kk++) {
            int kc = kk * 4 + q;
            f16x8 av[2], bv[4];
#pragma unroll
            for (int i = 0; i < 2; i++) {
                int row = wm * 32 + i * 16 + fr;
                av[i] = (s < 2) ? fA[i][s][kk]
                                : *(const f16x8*)&S0l[row * 64 + ((kc ^ (row & 7)) * 8)];
            }
#pragma unroll
            for (int j = 0; j < 4; j++) {
                int tc = wn * 64 + j * 16 + fr;
                bv[j] = *(const f16x8*)&Bp[tc * 192 + (s * 8 + (kc ^ (tc & 7))) * 8];
            }
#pragma unroll
            for (int i = 0; i < 2; i++)
#pragma unroll
                for (int j = 0; j < 4; j++)
                    acc[i][j] = __builtin_amdgcn_mfma_f32_16x16x32_f16(av[i], bv[j], acc[i][j], 0, 0, 0);
        }

    // ---- epilogue: Y tile -> LDS [128][136] -> f16x8 coalesced stores ----
    __syncthreads();                      // B7: all MFMA LDS reads done; smem free
#pragma unroll
    for (int i = 0; i < 2; i++)
#pragma unroll
        for (int j = 0; j < 4; j++)
#pragma unroll
            for (int tt = 0; tt < 4; tt++) {
                int row = wm * 32 + i * 16 + q * 4 + tt;
                int col = wn * 64 + j * 16 + fr;
                smem[row * 136 + col] = (_Float16)acc[i][j][tt];
            }
    __syncthreads();                      // B8
    _Float16* Yp = YT + (size_t)h * BT_ + (size_t)mh * 16384;
#pragma unroll
    for (int k2 = 0; k2 < 4; k2++) {
        int ch = tid + 512 * k2;          // 2048 = 128 rows x 16 chunks
        int r = ch >> 4, c8 = ch & 15;
        *(f16x8*)(Yp + (size_t)r * 128 + c8 * 8) = *(const f16x8*)&smem[r * 136 + c8 * 8];
    }
}

// ---------------- FFN GEMM in h-major: OutT[n][bt] = relu(sum_k WT[n][k]*YT[k][bt]) ----------------
// 512-thread blocks, 128n x 256bt tiles, grid 512 linear = 2 blocks/CU, no tail.
// XCD-chunked swizzle: HW round-robins blockIdx across the 8 XCDs (xcd = bid % 8);
// XCD x gets the 64 (bt0,bn) pairs with bt-slice in [16x,16x+16): YT working set
// = 4MB = one L2; the 4 bn-sharers of a slice are dispatch-adjacent on that XCD.
__global__ __launch_bounds__(512, 4) void ffn_gemm_T(
    const _Float16* __restrict__ WT,   // [512 n][512 k]
    const _Float16* __restrict__ YT,   // [512 k][BT_]
    _Float16* __restrict__ OT)         // [512 n][BT_], relu applied
{
    __shared__ __align__(16) _Float16 pool[29184];   // As[3][4096] + Bs[2][8448] = 58368 B
    _Float16* As0 = pool;
    _Float16* Bs0 = pool + 12288;
    const int tid = threadIdx.x;
    const int l = tid & 63, w = tid >> 6;            // 8 waves
    const int bid = blockIdx.x;                      // 512 linear
    const int xcd = bid & 7, slot = bid >> 3;        // bijective XCD-chunk map
    const int bt0 = (xcd * 16 + (slot >> 2)) * 256;
    const int bn  = (slot & 3) * 128;
    const int srow = l >> 2, schunk = (l & 3) ^ ((l >> 3) & 3);
    const _Float16* ga0 = WT + (size_t)(bn + w * 16 + srow) * H_ + schunk * 8;
    const int btg = tid & 15, kp = (tid >> 4) & 15, bth = tid >> 8;
    const _Float16* gb = YT + (size_t)(kp * 2) * BT_ + bt0 + bth * 128 + btg * 8;

    f16x8 stB[2][2];                     // [stage = k&1][b0/b1]; static idx under unroll
    f32x4 acc[4][4] = {};

    auto loadB = [&](int ks, int st) {
        stB[st][0] = *(const f16x8*)(gb + (size_t)(ks * 32) * BT_);
        stB[st][1] = *(const f16x8*)(gb + (size_t)(ks * 32 + 1) * BT_);
    };
    auto stageA = [&](int ks, int buf) {
        gload16(ga0 + ks * 32, As0 + buf * 4096 + w * 512);
    };
    auto writeB = [&](int st, int buf) {
        const int kpc = kp >> 2, kps = kp & 3;
#pragma unroll
        for (int e = 0; e < 8; e++) {
            int row = bth * 128 + btg * 8 + e;
            int off = row * 32 + (row >> 3) * 8 + ((kpc ^ ((row >> 1) & 3)) * 8) + kps * 2;
            _Float16 lo = stB[st][0][e], hi = stB[st][1][e];
            unsigned v = (unsigned)__builtin_bit_cast(unsigned short, lo)
                       | ((unsigned)__builtin_bit_cast(unsigned short, hi) << 16);
            *(unsigned*)&Bs0[buf * 8448 + off] = v;
        }
    };

    // prologue: B k=0,1 to regs; A k=0,1 staged; write B k=0
    loadB(0, 0);
    loadB(1, 1);
    __builtin_amdgcn_sched_barrier(0);
    stageA(0, 0);
    stageA(1, 1);
    writeB(0, 0);                         // implicit wait retires loadB(0)
    asm volatile("s_waitcnt vmcnt(1) lgkmcnt(0)" ::: "memory");   // As[0] ready; A(1) flies
    __builtin_amdgcn_s_barrier();
    asm volatile("" ::: "memory");

    const int wm = w >> 2, wn = w & 3;    // 2x4 waves, 64x64 tiles over 128x256
    const int fr = l & 15, q = l >> 4;
    const int axor = ((fr >> 1) & 3);
#pragma unroll
    for (int ks = 0; ks < 16; ks++) {
        const int a_cur = ks % 3;
        const int b_cur = ks & 1;
        if (ks + 2 < 16) {
            loadB(ks + 2, b_cur);                     // B before A: writeB's implicit wait
            __builtin_amdgcn_sched_barrier(0);        // won't drain the young stageA
            stageA(ks + 2, (ks + 2) % 3);
        }
        f16x8 av[4], bv[4];
#pragma unroll
        for (int i = 0; i < 4; i++) {
            int row = wm * 64 + i * 16 + fr;
            av[i] = *(const f16x8*)&As0[a_cur * 4096 + row * 32 + ((q ^ axor) * 8)];
        }
#pragma unroll
        for (int j = 0; j < 4; j++) {
            int row = wn * 64 + j * 16 + fr;
            bv[j] = *(const f16x8*)&Bs0[b_cur * 8448 + row * 32 + (row >> 3) * 8
                                        + ((q ^ ((row >> 1) & 3)) * 8)];
        }
#pragma unroll
        for (int i = 0; i < 4; i++)
#pragma unroll
            for (int j = 0; j < 4; j++)
                acc[i][j] = __builtin_amdgcn_mfma_f32_16x16x32_f16(av[i], bv[j], acc[i][j], 0, 0, 0);
        if (ks + 1 < 16) {
            writeB((ks + 1) & 1, b_cur ^ 1);          // Bs[b_cur^1] reads drained last barrier
            if (ks + 2 < 16)
                asm volatile("s_waitcnt vmcnt(3) lgkmcnt(0)" ::: "memory");  // A(ks+1) done; A(ks+2)+B(ks+2) fly
            else
                asm volatile("s_waitcnt vmcnt(0) lgkmcnt(0)" ::: "memory");  // tail: drain all
            __builtin_amdgcn_s_barrier();
            asm volatile("" ::: "memory");
        }
    }
    // close the pipeline before reusing pool for the epilogue
    asm volatile("s_waitcnt lgkmcnt(0)" ::: "memory");
    __builtin_amdgcn_s_barrier();
    asm volatile("" ::: "memory");

    // ---- epilogue: relu(C) -> LDS [64][264] per row-half -> f16x8 coalesced stores ----
#pragma unroll
    for (int half = 0; half < 2; half++) {
        if (half) __syncthreads();
        if (wm == half) {
#pragma unroll
            for (int i = 0; i < 4; i++)
#pragma unroll
                for (int j = 0; j < 4; j++)
#pragma unroll
                    for (int tt = 0; tt < 4; tt++) {
                        int r  = i * 16 + q * 4 + tt;          // 0..63 within half
                        int cc = wn * 64 + j * 16 + fr;        // 0..255
                        pool[r * 264 + cc] = (_Float16)fmaxf(acc[i][j][tt], 0.f);
                    }
        }
        __syncthreads();
#pragma unroll
        for (int k2 = 0; k2 < 4; k2++) {
            int ch = tid + 512 * k2;      // 2048 = 64 rows x 32 chunks
            int r = ch >> 5, c8 = ch & 31;
            *(f16x8*)(OT + (size_t)(bn + half * 64 + r) * BT_ + bt0 + c8 * 8) =
                *(const f16x8*)&pool[r * 264 + c8 * 8];
        }
    }
}

// ---------------- final head v2: 256 blocks = (b, 64-wide t-slice) ----------------
__global__ __launch_bounds__(512) void final_head2(const float* __restrict__ ylast,
                                                   const float* __restrict__ Wff3,
                                                   const float* __restrict__ Wdec,
                                                   float* __restrict__ out) {
    int bid = blockIdx.x;                 // 256 = 32 b x 8 s
    int b = bid >> 3, s = bid & 7;
    int tid = threadIdx.x;                // 512
    __shared__ float yrow[H_];
    __shared__ float hpart[8][64];
    yrow[tid] = ylast[(size_t)b * H_ + tid];
    __syncthreads();
    int kg = tid >> 6, tl = tid & 63;
    int t = s * 64 + tl;
    float acc = 0.f;
    const float* wcol = Wff3 + t;
    for (int k = kg * 64; k < kg * 64 + 64; k++)
        acc = fmaf(yrow[k], wcol[(size_t)k * H_], acc);
    hpart[kg][tl] = acc;
    __syncthreads();
    if (tid < 64) {
        float hv = 0.f;
#pragma unroll
        for (int g = 0; g < 8; g++) hv += hpart[g][tid];
        hv = fmaxf(hv, 0.f);              // h[t], t = s*64+tid, held by lane tid
#pragma unroll
        for (int d = 0; d < DOUT; d++) {
            float v = hv * Wdec[(size_t)(s * 64 + tid) * DOUT + d];
            v += __shfl_xor(v, 32); v += __shfl_xor(v, 16);
            v += __shfl_xor(v, 8);  v += __shfl_xor(v, 4);
            v += __shfl_xor(v, 2);  v += __shfl_xor(v, 1);
            if (tid == 0) atomicAdd(&out[(size_t)b * DOUT + d], v);
        }
    }
}

extern "C" void kernel_launch(void* const* d_in, const int* in_sizes, int n_in,
                              void* d_out, int out_size, void* d_ws, size_t ws_size,
                              hipStream_t stream) {
    const float* x      = (const float*)d_in[0];
    const float* Wenc   = (const float*)d_in[1];
    const float* log_dt = (const float*)d_in[2];
    const float* A_log  = (const float*)d_in[3];
    const float* Cmat   = (const float*)d_in[4];
    const float* Wff    = (const float*)d_in[5];
    const float* Wdec   = (const float*)d_in[6];
    float* out = (float*)d_out;

    char* ws = (char*)d_ws;
    _Float16* bufA  = (_Float16*)(ws);                   // 33554432 B  XT [512][32768]
    _Float16* bufB  = (_Float16*)(ws + 33554432);        // 33554432 B  YT
    _Float16* WT    = (_Float16*)(ws + 68681728);        // 1572864 B
    float*    ylast = (float*)(ws + 70254592);           // 65536 B

    for (int l = 0; l < NL; l++) {
        if (l < NL - 1) {
            conv_fused<<<H_ * 2, 512, 0, stream>>>(x, Wenc, log_dt, A_log, Cmat,
                                                   Wff + (size_t)l * H_ * H_,
                                                   WT + (size_t)l * H_ * H_,
                                                   bufA, bufB, ylast, out, l, 1);
            ffn_gemm_T<<<512, 512, 0, stream>>>(
                WT + (size_t)l * H_ * H_, bufB, bufA);
        } else {
            conv_fused<<<H_ * 2, 512, 0, stream>>>(x, Wenc, log_dt, A_log, Cmat,
                                                   Wff + (size_t)l * H_ * H_,
                                                   WT,           // unused (doY=0, layer==3)
                                                   bufA, bufB, ylast, out, l, 0);
            final_head2<<<B_ * 8, 512, 0, stream>>>(ylast, Wff + (size_t)l * H_ * H_, Wdec, out);
        }
    }
}